// Round 1
// 293.780 us; speedup vs baseline: 1.0469x; 1.0469x over previous
//
#include <hip/hip_runtime.h>
#include <hip/hip_bf16.h>

#define B_ 4
#define S_ 2048
#define E_ 1024
#define H_ 8
#define D_ 128

using f16x8 = __attribute__((ext_vector_type(8))) _Float16;
using f32x4 = __attribute__((ext_vector_type(4))) float;

__device__ __forceinline__ ushort f2h_bits(float f) {
    union { _Float16 h; ushort u; } cv; cv.h = (_Float16)f; return cv.u;
}
__device__ __forceinline__ f16x8 pack8(const float* __restrict__ p) {
    float4 f0 = *(const float4*)p;
    float4 f1 = *(const float4*)(p + 4);
    f16x8 r;
    r[0] = (_Float16)f0.x; r[1] = (_Float16)f0.y;
    r[2] = (_Float16)f0.z; r[3] = (_Float16)f0.w;
    r[4] = (_Float16)f1.x; r[5] = (_Float16)f1.y;
    r[6] = (_Float16)f1.z; r[7] = (_Float16)f1.w;
    return r;
}

// ---------------- K/V projection ----------------
// grid: (B*S/128, H), block 256.
// K out: [B,H,S,D] fp16. V out TRANSPOSED: [B,H,D,S] fp16.
// Epilogues repack through LDS for b128 coalesced global stores.
__global__ __launch_bounds__(256) void kv_proj(
    const float* __restrict__ seq,
    const float* __restrict__ Wk, const float* __restrict__ Wv,
    const float* __restrict__ bk, const float* __restrict__ bv,
    ushort* __restrict__ ko, ushort* __restrict__ vo)
{
    constexpr int TS = 136;
    __shared__ ushort Tk[128 * TS];   // [s_local][d]  (swizzled cols)
    __shared__ ushort Tv[128 * TS];   // [d][s_local]
    const int m0 = blockIdx.x * 128, h = blockIdx.y;
    const int tid = threadIdx.x, lane = tid & 63, w = tid >> 6;
    const int l16 = lane & 15, quad = lane >> 4;

    // A-frags: A[m=lane&15][k=quad*8+j]
    f16x8 a[2][4];
    #pragma unroll
    for (int mt = 0; mt < 2; ++mt)
        #pragma unroll
        for (int ks = 0; ks < 4; ++ks)
            a[mt][ks] = pack8(&seq[(size_t)(m0 + w * 32 + mt * 16 + l16) * E_
                                   + h * D_ + ks * 32 + quad * 8]);

    // ---- K ----
    {
        const float* W = Wk + (size_t)h * D_ * D_;
        f32x4 acc[2][8];
        #pragma unroll
        for (int mt = 0; mt < 2; ++mt)
            #pragma unroll
            for (int nt = 0; nt < 8; ++nt) { f32x4 z = {0.f,0.f,0.f,0.f}; acc[mt][nt] = z; }
        #pragma unroll
        for (int ks = 0; ks < 4; ++ks)
            #pragma unroll
            for (int nt = 0; nt < 8; ++nt) {
                f16x8 bfr = pack8(&W[(size_t)(nt * 16 + l16) * D_ + ks * 32 + quad * 8]);
                #pragma unroll
                for (int mt = 0; mt < 2; ++mt)
                    acc[mt][nt] = __builtin_amdgcn_mfma_f32_16x16x32_f16(
                        a[mt][ks], bfr, acc[mt][nt], 0, 0, 0);
            }
        #pragma unroll
        for (int nt = 0; nt < 8; ++nt) {
            int o = nt * 16 + l16;
            float bias = bk[h * D_ + o];
            #pragma unroll
            for (int mt = 0; mt < 2; ++mt)
                #pragma unroll
                for (int r = 0; r < 4; ++r) {
                    int row = w * 32 + mt * 16 + quad * 4 + r;
                    Tk[row * TS + (o ^ (quad << 3))] = f2h_bits(acc[mt][nt][r] + bias);
                }
        }
    }
    // ---- V ----
    {
        const float* W = Wv + (size_t)h * D_ * D_;
        f32x4 acc[2][8];
        #pragma unroll
        for (int mt = 0; mt < 2; ++mt)
            #pragma unroll
            for (int nt = 0; nt < 8; ++nt) { f32x4 z = {0.f,0.f,0.f,0.f}; acc[mt][nt] = z; }
        #pragma unroll
        for (int ks = 0; ks < 4; ++ks)
            #pragma unroll
            for (int nt = 0; nt < 8; ++nt) {
                f16x8 bfr = pack8(&W[(size_t)(nt * 16 + l16) * D_ + ks * 32 + quad * 8]);
                #pragma unroll
                for (int mt = 0; mt < 2; ++mt)
                    acc[mt][nt] = __builtin_amdgcn_mfma_f32_16x16x32_f16(
                        a[mt][ks], bfr, acc[mt][nt], 0, 0, 0);
            }
        #pragma unroll
        for (int nt = 0; nt < 8; ++nt) {
            int o = nt * 16 + l16;
            float bias = bv[h * D_ + o];
            #pragma unroll
            for (int mt = 0; mt < 2; ++mt)
                #pragma unroll
                for (int r = 0; r < 4; ++r) {
                    int row = w * 32 + mt * 16 + quad * 4 + r;
                    Tv[o * TS + row] = f2h_bits(acc[mt][nt][r] + bias);
                }
        }
    }
    __syncthreads();

    // coalesced b128 stores
    #pragma unroll
    for (int i = 0; i < 8; ++i) {
        int idx = tid + i * 256;
        int row = idx >> 4, c8 = (idx & 15) * 8;
        // K: logical [row][c8..c8+7] lives at swizzled chunk
        uint4 dk = *(uint4*)&Tk[row * TS + (c8 ^ (((row >> 2) & 3) << 3))];
        int m = m0 + row, bi = m >> 11, s = m & (S_ - 1);
        *(uint4*)&ko[(((size_t)bi * H_ + h) * S_ + s) * D_ + c8] = dk;
        // V: [d=row][s_local c8..c8+7]
        uint4 dv = *(uint4*)&Tv[row * TS + c8];
        int mg = m0 + c8, bv_i = mg >> 11, s0 = mg & (S_ - 1);
        *(uint4*)&vo[(((size_t)bv_i * H_ + h) * D_ + row) * S_ + s0] = dv;
    }
}

// ---------------- Flash attention (swapped-operand) ----------------
// grid: (S/128, H, B), block 256 (4 waves, 32 Q-rows each). BN = 128.
// QK^T computed SWAPPED: sacc = mfma(K_frag, Q_frag) -> C[row=s][col=q].
// Each lane then owns 32 s-values of a single q-row (q = w*32+mt*16+l16):
//   * row max/sum are lane-local (+2 cross-quad shuffles), not 16-lane reduces
//   * P is emitted as P^T[q][s]: 16 ds_write_b64 instead of 64 ds_write_b16
//   * PV: O^T = mfma(Vt_frag, Pt_frag); epilogue writes float4 per (mt,nt)
// Defer-max (THR=8 in log2 domain): skip o_acc rescale unless max grew; P<=256 (f16 safe).
// LDS: K tile [128][136] (aliased by Q tile phase 0 and by P^T each iter)
//      + Vt tile [128][136]  => 69632 B => 2 blocks/CU.
__global__ __launch_bounds__(256) void attn(
    const float* __restrict__ seq, const float* __restrict__ Wq,
    const float* __restrict__ bq,
    const ushort* __restrict__ kg, const ushort* __restrict__ vtg,
    float* __restrict__ out)
{
    constexpr int KS = 136;
    constexpr int VS = 136;
    __shared__ alignas(16) ushort smem[128 * KS + 128 * VS]; // 69632 B
    ushort* const Klds = smem;            // [s=128][d=136]; P^T[q=128][s=136] and Q alias this
    ushort* const Vt   = smem + 128 * KS; // [d=128][s=128+pad]

    const int m0 = blockIdx.x * 128;
    const int h = blockIdx.y, bi = blockIdx.z;
    const int bh = bi * H_ + h;
    const int tid = threadIdx.x, lane = tid & 63, w = tid >> 6;
    const int l16 = lane & 15, quad = lane >> 4;
    const size_t baseK = (size_t)bh * S_ * D_;
    const size_t baseV = (size_t)bh * D_ * S_;
    const float qscale = 0.35355339059327373f * 1.4426950408889634f; // 1/sqrt(8)*log2e
    const int qq_r = (l16 >> 2) & 3;   // read-side swizzle for Q frag rows

    // ---- Phase 0: Q tile = X Wq^T + bq (scaled), via swizzled Q region ----
    {
        f16x8 xa[2][4];
        #pragma unroll
        for (int mt = 0; mt < 2; ++mt)
            #pragma unroll
            for (int ks = 0; ks < 4; ++ks)
                xa[mt][ks] = pack8(&seq[((size_t)bi * S_ + m0 + w * 32 + mt * 16 + l16) * E_
                                        + h * D_ + ks * 32 + quad * 8]);
        f32x4 qacc[2][8];
        #pragma unroll
        for (int mt = 0; mt < 2; ++mt)
            #pragma unroll
            for (int nt = 0; nt < 8; ++nt) { f32x4 z = {0.f,0.f,0.f,0.f}; qacc[mt][nt] = z; }
        const float* W = Wq + (size_t)h * D_ * D_;
        #pragma unroll
        for (int ks = 0; ks < 4; ++ks)
            #pragma unroll
            for (int nt = 0; nt < 8; ++nt) {
                f16x8 bfr = pack8(&W[(size_t)(nt * 16 + l16) * D_ + ks * 32 + quad * 8]);
                #pragma unroll
                for (int mt = 0; mt < 2; ++mt)
                    qacc[mt][nt] = __builtin_amdgcn_mfma_f32_16x16x32_f16(
                        xa[mt][ks], bfr, qacc[mt][nt], 0, 0, 0);
            }
        #pragma unroll
        for (int nt = 0; nt < 8; ++nt) {
            int o = nt * 16 + l16;
            float bias = bq[h * D_ + o];
            #pragma unroll
            for (int mt = 0; mt < 2; ++mt)
                #pragma unroll
                for (int r = 0; r < 4; ++r) {
                    int row = w * 32 + mt * 16 + quad * 4 + r;
                    Klds[row * KS + (o ^ (quad << 3))] =
                        f2h_bits((qacc[mt][nt][r] + bias) * qscale);
                }
        }
    }
    __syncthreads();

    // qf[mt][ks]: Q[q = w*32+mt*16+l16][d = ks*32+quad*8+j]
    // (serves as B-operand of swapped QK^T: B[k=d][n=q] by A/B layout symmetry)
    f16x8 qf[2][4];
    #pragma unroll
    for (int mt = 0; mt < 2; ++mt)
        #pragma unroll
        for (int ks = 0; ks < 4; ++ks)
            qf[mt][ks] = *(const f16x8*)&Klds[(w * 32 + mt * 16 + l16) * KS
                                              + ks * 32 + ((quad ^ qq_r) << 3)];

    // o_acc[mt][nt]: O^T -> d = nt*16+quad*4+r, q = w*32+mt*16+l16
    f32x4 o_acc[2][8];
    #pragma unroll
    for (int mt = 0; mt < 2; ++mt)
        #pragma unroll
        for (int nt = 0; nt < 8; ++nt) { f32x4 z = {0.f,0.f,0.f,0.f}; o_acc[mt][nt] = z; }
    float m_prev[2] = {-1e30f, -1e30f};
    float l_lane[2] = {0.f, 0.f};   // per-lane partial row sum (this quad's s-subset)

    for (int j = 0; j < S_ / 128; ++j) {
        const int n0 = j * 128;
        __syncthreads();   // A: prior PV (and phase-0 qf) reads done
        // stage K [128][128] (unswizzled)
        #pragma unroll
        for (int i = 0; i < 8; ++i) {
            int idx = tid + i * 256;
            int r = idx >> 4, c8 = (idx & 15) * 8;
            *(uint4*)&Klds[r * KS + c8] =
                *(const uint4*)&kg[baseK + (size_t)(n0 + r) * D_ + c8];
        }
        // stage Vt [d=128][s=128] from pre-transposed global
        #pragma unroll
        for (int i = 0; i < 8; ++i) {
            int idx = tid + i * 256;
            int d = idx >> 4, c8 = (idx & 15) * 8;
            *(uint4*)&Vt[d * VS + c8] =
                *(const uint4*)&vtg[baseV + (size_t)d * S_ + n0 + c8];
        }
        __syncthreads();   // B

        // S^T = K Q^T: sacc[mt][nt]: s = nt*16+quad*4+r, q = w*32+mt*16+l16
        f32x4 sacc[2][8];
        #pragma unroll
        for (int mt = 0; mt < 2; ++mt)
            #pragma unroll
            for (int nt = 0; nt < 8; ++nt) { f32x4 z = {0.f,0.f,0.f,0.f}; sacc[mt][nt] = z; }
        __builtin_amdgcn_s_setprio(1);
        #pragma unroll
        for (int ks = 0; ks < 4; ++ks)
            #pragma unroll
            for (int nt = 0; nt < 8; ++nt) {
                f16x8 kf = *(const f16x8*)&Klds[(nt * 16 + l16) * KS + ks * 32 + quad * 8];
                #pragma unroll
                for (int mt = 0; mt < 2; ++mt)
                    sacc[mt][nt] = __builtin_amdgcn_mfma_f32_16x16x32_f16(
                        kf, qf[mt][ks], sacc[mt][nt], 0, 0, 0);
            }
        __builtin_amdgcn_s_setprio(0);

        // online softmax — s-values are lane-local; packed P^T f16 pairs
        uint2 pkw[2][8];
        #pragma unroll
        for (int mt = 0; mt < 2; ++mt) {
            float mx4[8];
            #pragma unroll
            for (int nt = 0; nt < 8; ++nt)
                mx4[nt] = fmaxf(fmaxf(sacc[mt][nt][0], sacc[mt][nt][1]),
                                fmaxf(sacc[mt][nt][2], sacc[mt][nt][3]));
            float mx = fmaxf(fmaxf(fmaxf(mx4[0], mx4[1]), fmaxf(mx4[2], mx4[3])),
                             fmaxf(fmaxf(mx4[4], mx4[5]), fmaxf(mx4[6], mx4[7])));
            mx = fmaxf(mx, __shfl_xor(mx, 16));
            mx = fmaxf(mx, __shfl_xor(mx, 32));
            // defer-max: only rescale when some row's max grew past THR=8 (log2 domain)
            if (__any(mx > m_prev[mt] + 8.0f)) {
                float mnew  = fmaxf(m_prev[mt], mx);
                float alpha = exp2f(m_prev[mt] - mnew);
                #pragma unroll
                for (int nt = 0; nt < 8; ++nt)
                    #pragma unroll
                    for (int r = 0; r < 4; ++r) o_acc[mt][nt][r] *= alpha;
                l_lane[mt] *= alpha;
                m_prev[mt] = mnew;
            }
            #pragma unroll
            for (int nt = 0; nt < 8; ++nt) {
                float e0 = exp2f(sacc[mt][nt][0] - m_prev[mt]);
                float e1 = exp2f(sacc[mt][nt][1] - m_prev[mt]);
                float e2 = exp2f(sacc[mt][nt][2] - m_prev[mt]);
                float e3 = exp2f(sacc[mt][nt][3] - m_prev[mt]);
                auto p01 = __builtin_amdgcn_cvt_pkrtz(e0, e1);
                auto p23 = __builtin_amdgcn_cvt_pkrtz(e2, e3);
                // denominator sees the same f16 quantization as the numerator
                l_lane[mt] += (float)p01[0] + (float)p01[1]
                            + (float)p23[0] + (float)p23[1];
                pkw[mt][nt] = make_uint2(__builtin_bit_cast(uint, p01),
                                         __builtin_bit_cast(uint, p23));
            }
        }

        __syncthreads();   // C: all waves done reading Klds; P^T may overwrite
        // P^T[q][s] writes: lane's 4 s-contiguous values -> one b64, bank-balanced.
        // Rows are wave-private; same-wave DS ordering covers the PV reads below.
        #pragma unroll
        for (int mt = 0; mt < 2; ++mt) {
            const int qrow = w * 32 + mt * 16 + l16;
            #pragma unroll
            for (int nt = 0; nt < 8; ++nt)
                *(uint2*)&Klds[qrow * KS + nt * 16 + quad * 4] = pkw[mt][nt];
        }

        // O^T += V^T P^T  (A = Vt frag, B = P^T frag from own rows)
        __builtin_amdgcn_s_setprio(1);
        #pragma unroll
        for (int ks = 0; ks < 4; ++ks) {
            f16x8 pb[2];
            #pragma unroll
            for (int mt = 0; mt < 2; ++mt)
                pb[mt] = *(const f16x8*)&Klds[(w * 32 + mt * 16 + l16) * KS
                                              + ks * 32 + quad * 8];
            #pragma unroll
            for (int nt = 0; nt < 8; ++nt) {
                f16x8 vf = *(const f16x8*)&Vt[(nt * 16 + l16) * VS + ks * 32 + quad * 8];
                #pragma unroll
                for (int mt = 0; mt < 2; ++mt)
                    o_acc[mt][nt] = __builtin_amdgcn_mfma_f32_16x16x32_f16(
                        vf, pb[mt], o_acc[mt][nt], 0, 0, 0);
            }
        }
        __builtin_amdgcn_s_setprio(0);
    }

    // epilogue: complete l across quads, O/l, float4 stores to fp32 [B,S,E]
    #pragma unroll
    for (int mt = 0; mt < 2; ++mt) {
        float l = l_lane[mt];
        l += __shfl_xor(l, 16);
        l += __shfl_xor(l, 32);
        float rinv = 1.0f / l;
        const int q = m0 + w * 32 + mt * 16 + l16;
        #pragma unroll
        for (int nt = 0; nt < 8; ++nt) {
            float4 o;
            o.x = o_acc[mt][nt][0] * rinv;
            o.y = o_acc[mt][nt][1] * rinv;
            o.z = o_acc[mt][nt][2] * rinv;
            o.w = o_acc[mt][nt][3] * rinv;
            *(float4*)&out[((size_t)bi * S_ + q) * E_ + h * D_ + nt * 16 + quad * 4] = o;
        }
    }
}

extern "C" void kernel_launch(void* const* d_in, const int* in_sizes, int n_in,
                              void* d_out, int out_size, void* d_ws, size_t ws_size,
                              hipStream_t stream) {
    const float* seq = (const float*)d_in[0];
    const float* Wq  = (const float*)d_in[1];
    const float* Wk  = (const float*)d_in[2];
    const float* Wv  = (const float*)d_in[3];
    const float* bq  = (const float*)d_in[4];
    const float* bk  = (const float*)d_in[5];
    const float* bv  = (const float*)d_in[6];

    const size_t per = (size_t)B_ * H_ * S_ * D_;      // 8M elements
    if (ws_size < 2 * per * sizeof(ushort)) return;    // need 32 MB
    ushort* kws  = (ushort*)d_ws;          // [B,H,S,D]
    ushort* vtws = kws + per;              // [B,H,D,S] (transposed)

    kv_proj<<<dim3(B_ * S_ / 128, H_), 256, 0, stream>>>(
        seq, Wk, Wv, bk, bv, kws, vtws);
    attn<<<dim3(S_ / 128, H_, B_), 256, 0, stream>>>(
        seq, Wq, bq, kws, vtws, (float*)d_out);
}

// Round 2
// 279.550 us; speedup vs baseline: 1.1002x; 1.0509x over previous
//
#include <hip/hip_runtime.h>
#include <hip/hip_bf16.h>

#define B_ 4
#define S_ 2048
#define E_ 1024
#define H_ 8
#define D_ 128

using f16x8 = __attribute__((ext_vector_type(8))) _Float16;
using f32x4 = __attribute__((ext_vector_type(4))) float;

__device__ __forceinline__ ushort f2h_bits(float f) {
    union { _Float16 h; ushort u; } cv; cv.h = (_Float16)f; return cv.u;
}
__device__ __forceinline__ f16x8 pack8(const float* __restrict__ p) {
    float4 f0 = *(const float4*)p;
    float4 f1 = *(const float4*)(p + 4);
    f16x8 r;
    r[0] = (_Float16)f0.x; r[1] = (_Float16)f0.y;
    r[2] = (_Float16)f0.z; r[3] = (_Float16)f0.w;
    r[4] = (_Float16)f1.x; r[5] = (_Float16)f1.y;
    r[6] = (_Float16)f1.z; r[7] = (_Float16)f1.w;
    return r;
}

// direct global->LDS DMA, 16B per lane; LDS dest is wave-uniform base + lane*16
__device__ __forceinline__ void gll16(const ushort* g, ushort* l) {
    __builtin_amdgcn_global_load_lds(
        (const __attribute__((address_space(1))) unsigned int*)g,
        (__attribute__((address_space(3))) unsigned int*)l, 16, 0, 0);
}

// ---------------- K/V projection ----------------
// grid: (B*S/128, H), block 256.
// K out: [B,H,S,D] fp16, PRE-SWIZZLED: within each s-row, 8-elem chunk at
//   position p holds logical chunk p ^ (s&7)  (so attn can DMA linearly into
//   a stride-128 LDS tile and read conflict-free).
// V out TRANSPOSED [B,H,D,S] fp16, pre-swizzled within each 128-s block:
//   position p holds logical chunk p ^ (d&7).
__global__ __launch_bounds__(256) void kv_proj(
    const float* __restrict__ seq,
    const float* __restrict__ Wk, const float* __restrict__ Wv,
    const float* __restrict__ bk, const float* __restrict__ bv,
    ushort* __restrict__ ko, ushort* __restrict__ vo)
{
    constexpr int TS = 136;
    __shared__ ushort Tk[128 * TS];   // [s_local][d]  (swizzled cols)
    __shared__ ushort Tv[128 * TS];   // [d][s_local]
    const int m0 = blockIdx.x * 128, h = blockIdx.y;
    const int tid = threadIdx.x, lane = tid & 63, w = tid >> 6;
    const int l16 = lane & 15, quad = lane >> 4;

    // A-frags: A[m=lane&15][k=quad*8+j]
    f16x8 a[2][4];
    #pragma unroll
    for (int mt = 0; mt < 2; ++mt)
        #pragma unroll
        for (int ks = 0; ks < 4; ++ks)
            a[mt][ks] = pack8(&seq[(size_t)(m0 + w * 32 + mt * 16 + l16) * E_
                                   + h * D_ + ks * 32 + quad * 8]);

    // ---- K ----
    {
        const float* W = Wk + (size_t)h * D_ * D_;
        f32x4 acc[2][8];
        #pragma unroll
        for (int mt = 0; mt < 2; ++mt)
            #pragma unroll
            for (int nt = 0; nt < 8; ++nt) { f32x4 z = {0.f,0.f,0.f,0.f}; acc[mt][nt] = z; }
        #pragma unroll
        for (int ks = 0; ks < 4; ++ks)
            #pragma unroll
            for (int nt = 0; nt < 8; ++nt) {
                f16x8 bfr = pack8(&W[(size_t)(nt * 16 + l16) * D_ + ks * 32 + quad * 8]);
                #pragma unroll
                for (int mt = 0; mt < 2; ++mt)
                    acc[mt][nt] = __builtin_amdgcn_mfma_f32_16x16x32_f16(
                        a[mt][ks], bfr, acc[mt][nt], 0, 0, 0);
            }
        #pragma unroll
        for (int nt = 0; nt < 8; ++nt) {
            int o = nt * 16 + l16;
            float bias = bk[h * D_ + o];
            #pragma unroll
            for (int mt = 0; mt < 2; ++mt)
                #pragma unroll
                for (int r = 0; r < 4; ++r) {
                    int row = w * 32 + mt * 16 + quad * 4 + r;
                    Tk[row * TS + (o ^ (quad << 3))] = f2h_bits(acc[mt][nt][r] + bias);
                }
        }
    }
    // ---- V ----
    {
        const float* W = Wv + (size_t)h * D_ * D_;
        f32x4 acc[2][8];
        #pragma unroll
        for (int mt = 0; mt < 2; ++mt)
            #pragma unroll
            for (int nt = 0; nt < 8; ++nt) { f32x4 z = {0.f,0.f,0.f,0.f}; acc[mt][nt] = z; }
        #pragma unroll
        for (int ks = 0; ks < 4; ++ks)
            #pragma unroll
            for (int nt = 0; nt < 8; ++nt) {
                f16x8 bfr = pack8(&W[(size_t)(nt * 16 + l16) * D_ + ks * 32 + quad * 8]);
                #pragma unroll
                for (int mt = 0; mt < 2; ++mt)
                    acc[mt][nt] = __builtin_amdgcn_mfma_f32_16x16x32_f16(
                        a[mt][ks], bfr, acc[mt][nt], 0, 0, 0);
            }
        #pragma unroll
        for (int nt = 0; nt < 8; ++nt) {
            int o = nt * 16 + l16;
            float bias = bv[h * D_ + o];
            #pragma unroll
            for (int mt = 0; mt < 2; ++mt)
                #pragma unroll
                for (int r = 0; r < 4; ++r) {
                    int row = w * 32 + mt * 16 + quad * 4 + r;
                    Tv[o * TS + row] = f2h_bits(acc[mt][nt][r] + bias);
                }
        }
    }
    __syncthreads();

    // coalesced b128 stores, applying the attn pre-swizzle
    #pragma unroll
    for (int i = 0; i < 8; ++i) {
        int idx = tid + i * 256;
        int row = idx >> 4, c8 = (idx & 15) * 8;
        // K: global position c8 must hold LOGICAL chunk (c8 ^ ((row&7)<<3));
        // that logical chunk lives in Tk at its own epilogue swizzle.
        int lk = c8 ^ ((row & 7) << 3);
        uint4 dk = *(uint4*)&Tk[row * TS + (lk ^ (((row >> 2) & 3) << 3))];
        int m = m0 + row, bi = m >> 11, s = m & (S_ - 1);
        *(uint4*)&ko[(((size_t)bi * H_ + h) * S_ + s) * D_ + c8] = dk;
        // V: position c8 holds logical s-chunk (c8 ^ ((d&7)<<3)), d = row
        uint4 dv = *(uint4*)&Tv[row * TS + (c8 ^ ((row & 7) << 3))];
        int mg = m0 + c8, bv_i = mg >> 11, s0 = mg & (S_ - 1);
        *(uint4*)&vo[(((size_t)bv_i * H_ + h) * D_ + row) * S_ + s0] = dv;
    }
}

// ---------------- Flash attention ----------------
// grid: (S/128, H, B), block 512 (8 waves, 16 Q-rows each). BN = 128.
// 1 barrier/iter: K,Vt double-buffered via global_load_lds DMA (prefetch for
// tile j+1 issued at top of iter j, drained by the end-of-iter barrier);
// P^T lives in a dedicated wave-private buffer (no aliasing barrier).
// All LDS tiles stride-128 with XOR chunk swizzle (globals pre-swizzled).
// LDS: K[2][128*128] + V[2][128*128] + P[128*128] = 160 KiB exactly, 1 blk/CU.
__global__ __launch_bounds__(512) void attn(
    const float* __restrict__ seq, const float* __restrict__ Wq,
    const float* __restrict__ bq,
    const ushort* __restrict__ kg, const ushort* __restrict__ vtg,
    float* __restrict__ out)
{
    __shared__ alignas(16) ushort Kbuf[2][128 * 128];
    __shared__ alignas(16) ushort Vbuf[2][128 * 128];
    __shared__ alignas(16) ushort Pbuf[128 * 128];   // P^T[q][s]; Q scratch in phase 0

    const int m0 = blockIdx.x * 128;
    const int h = blockIdx.y, bi = blockIdx.z;
    const int bh = bi * H_ + h;
    const int tid = threadIdx.x, lane = tid & 63, w = tid >> 6;
    const int l16 = lane & 15, quad = lane >> 4;
    const ushort* kbase = kg + (size_t)bh * S_ * D_;   // each 128-row tile contiguous 32 KB
    const ushort* vbase = vtg + (size_t)bh * D_ * S_;  // row stride S_
    const float qscale = 0.35355339059327373f * 1.4426950408889634f; // 1/sqrt(8)*log2e

    // ---- prologue: DMA tile 0 into buffer 0 (overlaps Q projection) ----
    #pragma unroll
    for (int i = 0; i < 4; ++i) {
        int b = i * 8 + w;
        gll16(kbase + (size_t)b * 512 + lane * 8, &Kbuf[0][0] + b * 512);
        gll16(vbase + (size_t)(b * 4 + (lane >> 4)) * S_ + (lane & 15) * 8,
              &Vbuf[0][0] + b * 512);
    }

    // ---- Phase 0: Q tile = X Wq^T + bq (scaled), transposed through Pbuf ----
    {
        f16x8 xa[4];
        #pragma unroll
        for (int ks = 0; ks < 4; ++ks)
            xa[ks] = pack8(&seq[((size_t)bi * S_ + m0 + w * 16 + l16) * E_
                                + h * D_ + ks * 32 + quad * 8]);
        f32x4 qacc[8];
        #pragma unroll
        for (int nt = 0; nt < 8; ++nt) { f32x4 z = {0.f,0.f,0.f,0.f}; qacc[nt] = z; }
        const float* W = Wq + (size_t)h * D_ * D_;
        #pragma unroll
        for (int ks = 0; ks < 4; ++ks)
            #pragma unroll
            for (int nt = 0; nt < 8; ++nt) {
                f16x8 bfr = pack8(&W[(size_t)(nt * 16 + l16) * D_ + ks * 32 + quad * 8]);
                qacc[nt] = __builtin_amdgcn_mfma_f32_16x16x32_f16(
                    xa[ks], bfr, qacc[nt], 0, 0, 0);
            }
        #pragma unroll
        for (int nt = 0; nt < 8; ++nt) {
            int o = nt * 16 + l16;
            float bias = bq[h * D_ + o];
            #pragma unroll
            for (int r = 0; r < 4; ++r) {
                int row = w * 16 + quad * 4 + r;
                Pbuf[row * 128 + (o ^ (quad << 3))] =
                    f2h_bits((qacc[nt][r] + bias) * qscale);
            }
        }
    }
    // qf[ks]: Q[q = w*16+l16][d = ks*32+quad*8..+7] (wave-private rows, same-wave order)
    f16x8 qf[4];
    #pragma unroll
    for (int ks = 0; ks < 4; ++ks)
        qf[ks] = *(const f16x8*)&Pbuf[(w * 16 + l16) * 128
                                      + ks * 32 + ((quad ^ (l16 >> 2)) << 3)];

    f32x4 o_acc[8];
    #pragma unroll
    for (int nt = 0; nt < 8; ++nt) { f32x4 z = {0.f,0.f,0.f,0.f}; o_acc[nt] = z; }
    float m_prev = -1e30f, l_lane = 0.f;

    __syncthreads();   // tile 0 DMA drained (barrier implies vmcnt(0))

    const int psw = (l16 & 7) << 1;          // P-row swizzle (4-elem groups)
    const int kvsw = l16 & 7;                // K/V chunk swizzle

    for (int j = 0; j < S_ / 128; ++j) {
        const int cur = j & 1;
        const ushort* KL = &Kbuf[cur][0];
        const ushort* VL = &Vbuf[cur][0];

        // prefetch tile j+1 (DMA; completes at this iter's end barrier)
        if (j + 1 < S_ / 128) {
            const int n1 = (j + 1) * 128;
            const ushort* kt = kbase + (size_t)n1 * D_;
            const ushort* vt = vbase + n1;
            ushort* kd = &Kbuf[cur ^ 1][0];
            ushort* vd = &Vbuf[cur ^ 1][0];
            #pragma unroll
            for (int i = 0; i < 4; ++i) {
                int b = i * 8 + w;
                gll16(kt + (size_t)b * 512 + lane * 8, kd + b * 512);
                gll16(vt + (size_t)(b * 4 + (lane >> 4)) * S_ + (lane & 15) * 8,
                      vd + b * 512);
            }
        }

        // S^T = K Q^T: sacc[nt]: s = nt*16+quad*4+r, q = w*16+l16
        f32x4 sacc[8];
        #pragma unroll
        for (int nt = 0; nt < 8; ++nt) { f32x4 z = {0.f,0.f,0.f,0.f}; sacc[nt] = z; }
        __builtin_amdgcn_s_setprio(1);
        #pragma unroll
        for (int ks = 0; ks < 4; ++ks)
            #pragma unroll
            for (int nt = 0; nt < 8; ++nt) {
                f16x8 kf = *(const f16x8*)&KL[(nt * 16 + l16) * 128
                                              + (((ks * 4 + quad) ^ kvsw) << 3)];
                sacc[nt] = __builtin_amdgcn_mfma_f32_16x16x32_f16(
                    kf, qf[ks], sacc[nt], 0, 0, 0);
            }
        __builtin_amdgcn_s_setprio(0);

        // online softmax — 32 s-values per lane, lane-local
        uint2 pkw[8];
        {
            float mx = fmaxf(fmaxf(sacc[0][0], sacc[0][1]), fmaxf(sacc[0][2], sacc[0][3]));
            #pragma unroll
            for (int nt = 1; nt < 8; ++nt)
                mx = fmaxf(mx, fmaxf(fmaxf(sacc[nt][0], sacc[nt][1]),
                                     fmaxf(sacc[nt][2], sacc[nt][3])));
            mx = fmaxf(mx, __shfl_xor(mx, 16));
            mx = fmaxf(mx, __shfl_xor(mx, 32));
            // defer-max: rescale only when max grew past THR=8 (log2 domain, P<=256)
            if (__any(mx > m_prev + 8.0f)) {
                float mnew  = fmaxf(m_prev, mx);
                float alpha = exp2f(m_prev - mnew);
                #pragma unroll
                for (int nt = 0; nt < 8; ++nt)
                    #pragma unroll
                    for (int r = 0; r < 4; ++r) o_acc[nt][r] *= alpha;
                l_lane *= alpha;
                m_prev = mnew;
            }
            #pragma unroll
            for (int nt = 0; nt < 8; ++nt) {
                float e0 = exp2f(sacc[nt][0] - m_prev);
                float e1 = exp2f(sacc[nt][1] - m_prev);
                float e2 = exp2f(sacc[nt][2] - m_prev);
                float e3 = exp2f(sacc[nt][3] - m_prev);
                auto p01 = __builtin_amdgcn_cvt_pkrtz(e0, e1);
                auto p23 = __builtin_amdgcn_cvt_pkrtz(e2, e3);
                // denominator sees the same f16 quantization as the numerator
                l_lane += (float)p01[0] + (float)p01[1] + (float)p23[0] + (float)p23[1];
                pkw[nt] = make_uint2(__builtin_bit_cast(uint, p01),
                                     __builtin_bit_cast(uint, p23));
            }
        }

        // P^T[q][s] writes: bank-balanced b64, wave-private rows (no barrier)
        const int qrow = w * 16 + l16;
        ushort* prow = &Pbuf[qrow * 128];
        #pragma unroll
        for (int nt = 0; nt < 8; ++nt)
            *(uint2*)&prow[((nt * 4 + quad) ^ psw) << 2] = pkw[nt];

        // O^T += V^T P^T
        __builtin_amdgcn_s_setprio(1);
        #pragma unroll
        for (int ks = 0; ks < 4; ++ks) {
            f16x8 pb = *(const f16x8*)&prow[((ks * 8 + quad * 2) ^ psw) << 2];
            #pragma unroll
            for (int nt = 0; nt < 8; ++nt) {
                f16x8 vf = *(const f16x8*)&VL[(nt * 16 + l16) * 128
                                              + (((ks * 4 + quad) ^ kvsw) << 3)];
                o_acc[nt] = __builtin_amdgcn_mfma_f32_16x16x32_f16(
                    vf, pb, o_acc[nt], 0, 0, 0);
            }
        }
        __builtin_amdgcn_s_setprio(0);

        __syncthreads();   // all reads of tile j done; tile j+1 DMA drained
    }

    // epilogue: complete l across quads, O/l, float4 stores to fp32 [B,S,E]
    {
        float l = l_lane;
        l += __shfl_xor(l, 16);
        l += __shfl_xor(l, 32);
        float rinv = 1.0f / l;
        const int q = m0 + w * 16 + l16;
        #pragma unroll
        for (int nt = 0; nt < 8; ++nt) {
            float4 o;
            o.x = o_acc[nt][0] * rinv;
            o.y = o_acc[nt][1] * rinv;
            o.z = o_acc[nt][2] * rinv;
            o.w = o_acc[nt][3] * rinv;
            *(float4*)&out[((size_t)bi * S_ + q) * E_ + h * D_ + nt * 16 + quad * 4] = o;
        }
    }
}

extern "C" void kernel_launch(void* const* d_in, const int* in_sizes, int n_in,
                              void* d_out, int out_size, void* d_ws, size_t ws_size,
                              hipStream_t stream) {
    const float* seq = (const float*)d_in[0];
    const float* Wq  = (const float*)d_in[1];
    const float* Wk  = (const float*)d_in[2];
    const float* Wv  = (const float*)d_in[3];
    const float* bq  = (const float*)d_in[4];
    const float* bk  = (const float*)d_in[5];
    const float* bv  = (const float*)d_in[6];

    const size_t per = (size_t)B_ * H_ * S_ * D_;      // 8M elements
    if (ws_size < 2 * per * sizeof(ushort)) return;    // need 32 MB
    ushort* kws  = (ushort*)d_ws;          // [B,H,S,D]   pre-swizzled
    ushort* vtws = kws + per;              // [B,H,D,S]   pre-swizzled

    kv_proj<<<dim3(B_ * S_ / 128, H_), 256, 0, stream>>>(
        seq, Wk, Wv, bk, bv, kws, vtws);
    attn<<<dim3(S_ / 128, H_, B_), 512, 0, stream>>>(
        seq, Wq, bq, kws, vtws, (float*)d_out);
}